// Round 8
// baseline (473.377 us; speedup 1.0000x reference)
//
#include <hip/hip_runtime.h>
#include <hip/hip_cooperative_groups.h>
#include <stdint.h>

namespace cg = cooperative_groups;

typedef __attribute__((ext_vector_type(4))) float f32x4;
typedef __attribute__((ext_vector_type(8))) short s16x8;

#define BB 4
#define NN 4096
#define FF 32
#define BNF (BB*NN*FF)   // 524288

// ---------- bf16 helpers ----------
static __device__ __forceinline__ float bf2f(uint16_t u) {
    union { uint32_t i; float f; } v; v.i = ((uint32_t)u) << 16; return v.f;
}
static __device__ __forceinline__ uint16_t f2bf(float f) {
    union { float f; uint32_t i; } v; v.f = f;
    uint32_t r = v.i + 0x7FFFu + ((v.i >> 16) & 1u);
    return (uint16_t)(r >> 16);
}
static __device__ __forceinline__ float sig_acc(float x) { return 1.0f / (1.0f + expf(-x)); }

// ---------- shared-memory phase union (44.2 KB max -> 2 blocks/CU fits) ----------
struct GemmSm { uint16_t aL[128 * 32]; uint16_t bL[128 * 32]; };       // 16 KB
struct PackSm { uint16_t tl[32][65]; };                                 // 4.2 KB
struct F1Sm { uint32_t WL[8192]; float BL[512]; float AL[32][65]; uint16_t H1[32][33]; }; // 45.2 KB... (32768+2048+8320+2112 = 45248B)
struct F2Sm { uint32_t WL[6144]; float BL[384]; float AL[32][65]; };
union SMem { GemmSm g; PackSm p; F1Sm f1; F2Sm f2; };

// ---------- pack body: state [B][N][F] fp32 -> dst[rowBase + b*32 + f][n] bf16 ----------
static __device__ __forceinline__ void pack_body(
    const float* __restrict__ src, uint16_t* __restrict__ dst,
    int b, int ntile, int rowBase, uint16_t tl[32][65], int t)
{
    int n0 = ntile * 64;
    {
        int i = t >> 2, ch = t & 3;
        size_t idx = ((size_t)(b * NN + n0 + i)) * FF + ch * 8;
        float4 v0 = *(const float4*)(src + idx);
        float4 v1 = *(const float4*)(src + idx + 4);
        uint16_t e[8] = { f2bf(v0.x), f2bf(v0.y), f2bf(v0.z), f2bf(v0.w),
                          f2bf(v1.x), f2bf(v1.y), f2bf(v1.z), f2bf(v1.w) };
        #pragma unroll
        for (int k = 0; k < 8; k++) tl[ch * 8 + k][i] = e[k];
    }
    __syncthreads();
    {
        int f = t >> 3, ch = t & 7;
        union { uint4 u; uint16_t e[8]; } v;
        #pragma unroll
        for (int k = 0; k < 8; k++) v.e[k] = tl[f][ch * 8 + k];
        size_t row = (size_t)(rowBase + b * 32 + f);
        *(uint4*)(dst + row * NN + n0 + ch * 8) = v.u;
    }
}

// ---------- GEMM body: partials [ks][m][c]; 128x128 tile, BK=32, reg prefetch ----------
static __device__ __forceinline__ void gemm_body(
    const uint16_t* __restrict__ A16, const uint16_t* __restrict__ Bt,
    float* __restrict__ part, int mt, int nt, int ks, GemmSm& g, int t)
{
    const int kLen = 512;
    int m0 = mt * 128, c0 = nt * 128, k0 = ks * kLen;
    int kend = k0 + kLen;
    uint16_t* aL = g.aL; uint16_t* bL = g.bL;
    int lane = t & 63, w = t >> 6;
    int wm = (w & 1) * 64, wn = (w >> 1) * 64;
    int lm = lane & 15, lk = lane >> 4;
    int pos0 = t * 16, pos1 = 4096 + t * 16;
    int row0 = pos0 >> 6, col0 = (pos0 & 63) >> 1;
    int row1 = pos1 >> 6, col1 = (pos1 & 63) >> 1;

    f32x4 acc[4][4] = {};
    uint4 va0 = *(const uint4*)(A16 + (size_t)(m0 + row0) * 4096 + k0 + col0);
    uint4 va1 = *(const uint4*)(A16 + (size_t)(m0 + row1) * 4096 + k0 + col1);
    uint4 vb0 = *(const uint4*)(Bt + (size_t)(c0 + row0) * 4096 + k0 + col0);
    uint4 vb1 = *(const uint4*)(Bt + (size_t)(c0 + row1) * 4096 + k0 + col1);

    for (int kk = k0; kk < kend; kk += 32) {
        if (kk != k0) __syncthreads();
        *(uint4*)((char*)aL + pos0) = va0;
        *(uint4*)((char*)aL + pos1) = va1;
        *(uint4*)((char*)bL + pos0) = vb0;
        *(uint4*)((char*)bL + pos1) = vb1;
        __syncthreads();
        int kn = kk + 32;
        if (kn < kend) {
            va0 = *(const uint4*)(A16 + (size_t)(m0 + row0) * 4096 + kn + col0);
            va1 = *(const uint4*)(A16 + (size_t)(m0 + row1) * 4096 + kn + col1);
            vb0 = *(const uint4*)(Bt + (size_t)(c0 + row0) * 4096 + kn + col0);
            vb1 = *(const uint4*)(Bt + (size_t)(c0 + row1) * 4096 + kn + col1);
        }
        s16x8 af[4], bfr[4];
        #pragma unroll
        for (int i = 0; i < 4; i++)
            af[i] = *(const s16x8*)(aL + (wm + i * 16 + lm) * 32 + lk * 8);
        #pragma unroll
        for (int j = 0; j < 4; j++)
            bfr[j] = *(const s16x8*)(bL + (wn + j * 16 + lm) * 32 + lk * 8);
        #pragma unroll
        for (int i = 0; i < 4; i++)
            #pragma unroll
            for (int j = 0; j < 4; j++)
                acc[i][j] = __builtin_amdgcn_mfma_f32_16x16x32_bf16(af[i], bfr[j], acc[i][j], 0, 0, 0);
    }

    int r4 = (lane >> 4) * 4;
    #pragma unroll
    for (int i = 0; i < 4; i++)
        #pragma unroll
        for (int j = 0; j < 4; j++) {
            int c = c0 + wn + j * 16 + lm;
            int mrb = m0 + wm + i * 16 + r4;
            #pragma unroll
            for (int r = 0; r < 4; r++)
                part[((size_t)ks * 4096 + mrb + r) * 256 + c] = acc[i][j][r];
        }
}

// ---------- stage: sum 8 split-K partials [ks][m][c] into AL[node][64] ----------
static __device__ __forceinline__ void stage_acts8(
    const float* __restrict__ part, int b, int n0, int t, float AL[32][65])
{
    int node = t >> 3, q = t & 7;
    int fa0 = q * 8;
    int cbase = (fa0 < 32) ? (b * 32 + fa0) : (128 + b * 32 + (fa0 - 32));
    float s[8] = {};
    #pragma unroll
    for (int k = 0; k < 8; k++) {
        const float* p = part + ((size_t)k * 4096 + n0 + node) * 256 + cbase;
        float4 v0 = *(const float4*)p;
        float4 v1 = *(const float4*)(p + 4);
        s[0] += v0.x; s[1] += v0.y; s[2] += v0.z; s[3] += v0.w;
        s[4] += v1.x; s[5] += v1.y; s[6] += v1.z; s[7] += v1.w;
    }
    #pragma unroll
    for (int k = 0; k < 8; k++) AL[node][fa0 + k] = s[k];
}

// ---------- fuse1 body: 8-gate GLU + LSTM; c_new (fp32) + packed h1 (bf16) ----------
static __device__ __forceinline__ void fuse1_body(
    const float* __restrict__ part, const float* __restrict__ Wf,
    const float* __restrict__ bf_, const float* __restrict__ cf,
    float* __restrict__ cnew, uint16_t* __restrict__ S2t,
    int b, int n0, F1Sm& s, int t)
{
    for (int i = t; i < 8192; i += 256) {
        int g = i >> 10, rem = i & 1023, f = rem >> 5, j = rem & 31;
        uint32_t lo = f2bf(Wf[g * 2048 + f * 64 + j]);
        uint32_t hi = f2bf(Wf[g * 2048 + f * 64 + 32 + j]);
        s.WL[i] = lo | (hi << 16);
    }
    if (t < 128) {
        #pragma unroll
        for (int k = 0; k < 4; k++) s.BL[t * 4 + k] = bf_[t * 4 + k];
    }
    stage_acts8(part, b, n0, t, s.AL);
    __syncthreads();

    int j = t & 31, nb = t >> 5;
    float acc[4][16];
    #pragma unroll
    for (int u = 0; u < 4; u++)
        #pragma unroll
        for (int g = 0; g < 8; g++) {
            acc[u][g * 2]     = s.BL[g * 64 + j];
            acc[u][g * 2 + 1] = s.BL[g * 64 + 32 + j];
        }
    #pragma unroll 2
    for (int f = 0; f < 32; f++) {
        float wls[8], wrs[8];
        #pragma unroll
        for (int g = 0; g < 8; g++) {
            uint32_t wv = s.WL[g * 1024 + f * 32 + j];
            wls[g] = __uint_as_float(wv << 16);
            wrs[g] = __uint_as_float(wv & 0xFFFF0000u);
        }
        #pragma unroll
        for (int u = 0; u < 4; u++) {
            int node = nb + u * 8;
            float ax = s.AL[node][f], ah = s.AL[node][32 + f];
            #pragma unroll
            for (int g = 0; g < 8; g++) {
                float src = (g & 1) ? ah : ax;
                acc[u][g * 2]     += src * wls[g];
                acc[u][g * 2 + 1] += src * wrs[g];
            }
        }
    }
    #pragma unroll
    for (int u = 0; u < 4; u++) {
        int node = nb + u * 8;
        float fx = acc[u][0]  * sig_acc(acc[u][1]);
        float fh = acc[u][2]  * sig_acc(acc[u][3]);
        float ix = acc[u][4]  * sig_acc(acc[u][5]);
        float ih = acc[u][6]  * sig_acc(acc[u][7]);
        float cx = acc[u][8]  * sig_acc(acc[u][9]);
        float ch = acc[u][10] * sig_acc(acc[u][11]);
        float ox = acc[u][12] * sig_acc(acc[u][13]);
        float oh = acc[u][14] * sig_acc(acc[u][15]);
        float fg = sig_acc(fx + fh), ig = sig_acc(ix + ih), og = sig_acc(ox + oh);
        size_t gidx = ((size_t)(b * NN + n0 + node)) * FF + j;
        float cvv = cf[gidx];
        float cn = fg * cvv + ig * tanhf(cx + ch);
        float h1 = og * tanhf(cn);
        cnew[gidx] = cn;
        s.H1[j][node] = f2bf(h1);
    }
    __syncthreads();
    {
        int fr = t >> 3, ch = t & 7;
        union { uint2 u; uint16_t e[4]; } v;
        #pragma unroll
        for (int k = 0; k < 4; k++) v.e[k] = s.H1[fr][ch * 4 + k];
        *(uint2*)(S2t + ((size_t)(b * 32 + fr)) * NN + n0 + ch * 4) = v.u;
    }
}

// ---------- fuse2 body: 6-gate GLU + memory-state; h_new, m_new (fp32) ----------
static __device__ __forceinline__ void fuse2_body(
    const float* __restrict__ part, const float* __restrict__ Wf,
    const float* __restrict__ bf_, const float* __restrict__ mf,
    float* __restrict__ hnew, float* __restrict__ mnew,
    int b, int n0, F2Sm& s, int t)
{
    for (int i = t; i < 6144; i += 256) {
        int g = i >> 10, rem = i & 1023, f = rem >> 5, j = rem & 31;
        int gg = 8 + g;
        uint32_t lo = f2bf(Wf[gg * 2048 + f * 64 + j]);
        uint32_t hi = f2bf(Wf[gg * 2048 + f * 64 + 32 + j]);
        s.WL[i] = lo | (hi << 16);
    }
    if (t < 96) {
        #pragma unroll
        for (int k = 0; k < 4; k++) s.BL[t * 4 + k] = bf_[512 + t * 4 + k];
    }
    stage_acts8(part, b, n0, t, s.AL);
    __syncthreads();

    int j = t & 31, nb = t >> 5;
    float acc[4][12];
    #pragma unroll
    for (int u = 0; u < 4; u++)
        #pragma unroll
        for (int g = 0; g < 6; g++) {
            acc[u][g * 2]     = s.BL[g * 64 + j];
            acc[u][g * 2 + 1] = s.BL[g * 64 + 32 + j];
        }
    #pragma unroll 2
    for (int f = 0; f < 32; f++) {
        float wls[6], wrs[6];
        #pragma unroll
        for (int g = 0; g < 6; g++) {
            uint32_t wv = s.WL[g * 1024 + f * 32 + j];
            wls[g] = __uint_as_float(wv << 16);
            wrs[g] = __uint_as_float(wv & 0xFFFF0000u);
        }
        #pragma unroll
        for (int u = 0; u < 4; u++) {
            int node = nb + u * 8;
            float ah1 = s.AL[node][f], am = s.AL[node][32 + f];
            #pragma unroll
            for (int g = 0; g < 6; g++) {
                float src = (g & 1) ? am : ah1;
                acc[u][g * 2]     += src * wls[g];
                acc[u][g * 2 + 1] += src * wrs[g];
            }
        }
    }
    #pragma unroll
    for (int u = 0; u < 4; u++) {
        int node = nb + u * 8;
        float sa_ih = acc[u][0]  * sig_acc(acc[u][1]);
        float sa_im = acc[u][2]  * sig_acc(acc[u][3]);
        float sa_gh = acc[u][4]  * sig_acc(acc[u][5]);
        float sa_gm = acc[u][6]  * sig_acc(acc[u][7]);
        float sa_oh = acc[u][8]  * sig_acc(acc[u][9]);
        float sa_om = acc[u][10] * sig_acc(acc[u][11]);
        float i2 = sig_acc(sa_ih + sa_im);
        float g2 = sig_acc(sa_gh + sa_gm);
        float o2 = sig_acc(sa_oh + sa_om);
        size_t gidx = ((size_t)(b * NN + n0 + node)) * FF + j;
        float mvv = mf[gidx];
        float mn = i2 * mvv + (1.0f - i2) * g2;
        float hn = mn * o2;
        mnew[gidx] = mn;
        hnew[gidx] = hn;
    }
}

// ---------- the cooperative mega-kernel: whole pipeline, 512 blocks ----------
__global__ __launch_bounds__(256, 2) void mega_kernel(
    const float* __restrict__ adj, const float* __restrict__ x,
    const float* __restrict__ h, const float* __restrict__ cin,
    const float* __restrict__ min_, const float* __restrict__ W,
    const float* __restrict__ bb, float* __restrict__ out,
    uint16_t* __restrict__ adjb, uint16_t* __restrict__ P,
    float* __restrict__ part)
{
    __shared__ SMem sm;
    cg::grid_group grid = cg::this_grid();
    int t = threadIdx.x;
    int bid = blockIdx.x;

    // phase 0: adj fp32 -> bf16 (all blocks) + pack x,h
    {
        size_t ft = (size_t)bid * 256 + t;
        #pragma unroll 2
        for (int p = 0; p < 16; p++) {
            size_t i = (ft + (size_t)p * 131072) * 8;
            float4 v0 = *(const float4*)(adj + i);
            float4 v1 = *(const float4*)(adj + i + 4);
            union { uint4 u; uint16_t e[8]; } o;
            o.e[0] = f2bf(v0.x); o.e[1] = f2bf(v0.y); o.e[2] = f2bf(v0.z); o.e[3] = f2bf(v0.w);
            o.e[4] = f2bf(v1.x); o.e[5] = f2bf(v1.y); o.e[6] = f2bf(v1.z); o.e[7] = f2bf(v1.w);
            *(uint4*)(adjb + i) = o.u;
        }
        int tensor = bid >> 8, b = (bid >> 6) & 3, ntile = bid & 63;
        pack_body(tensor ? h : x, P, b, ntile, tensor * 128, sm.p.tl, t);
    }
    grid.sync();
    // phase 1: GEMM1 (adj @ [x|h])
    gemm_body(adjb, P, part, bid & 31, (bid >> 5) & 1, bid >> 6, sm.g, t);
    grid.sync();
    // phase 2: fuse1 (c_new + h1 -> P rows 0..127) + pack m -> P rows 128..255
    {
        fuse1_body(part, W, bb, cin, out + BNF, P, bid >> 7, (bid & 127) * 32, sm.f1, t);
        __syncthreads();
        if (bid < 256)
            pack_body(min_, P, (bid >> 6) & 3, bid & 63, 128, sm.p.tl, t);
    }
    grid.sync();
    // phase 3: GEMM2 (adj @ [h1|m])
    gemm_body(adjb, P, part, bid & 31, (bid >> 5) & 1, bid >> 6, sm.g, t);
    grid.sync();
    // phase 4: fuse2 (h_new, m_new)
    fuse2_body(part, W, bb, min_, out, out + 2 * BNF, bid >> 7, (bid & 127) * 32, sm.f2, t);
}

// ---------- fallback multi-kernel wrappers (same validated bodies) ----------
__global__ __launch_bounds__(256) void cvt_adj_k(const float* __restrict__ a,
                                                 uint16_t* __restrict__ ab)
{
    size_t i = ((size_t)blockIdx.x * 256 + threadIdx.x) * 8;
    float4 v0 = *(const float4*)(a + i);
    float4 v1 = *(const float4*)(a + i + 4);
    union { uint4 u; uint16_t e[8]; } o;
    o.e[0] = f2bf(v0.x); o.e[1] = f2bf(v0.y); o.e[2] = f2bf(v0.z); o.e[3] = f2bf(v0.w);
    o.e[4] = f2bf(v1.x); o.e[5] = f2bf(v1.y); o.e[6] = f2bf(v1.z); o.e[7] = f2bf(v1.w);
    *(uint4*)(ab + i) = o.u;
}
__global__ __launch_bounds__(256) void pack_k(const float* __restrict__ s0,
                                              const float* __restrict__ s1,
                                              uint16_t* __restrict__ dst)
{
    __shared__ PackSm ps;
    int bid = blockIdx.x; int tensor = bid >> 8;
    pack_body(tensor ? s1 : s0, dst, (bid >> 6) & 3, bid & 63, tensor * 128, ps.tl, threadIdx.x);
}
__global__ __launch_bounds__(256) void gemm_k(const uint16_t* __restrict__ A16,
                                              const uint16_t* __restrict__ Bt,
                                              float* __restrict__ part)
{
    __shared__ GemmSm g;
    gemm_body(A16, Bt, part, blockIdx.x, blockIdx.y, blockIdx.z, g, threadIdx.x);
}
__global__ __launch_bounds__(256) void fuse1_k(const float* __restrict__ part,
    const float* __restrict__ W, const float* __restrict__ bb,
    const float* __restrict__ cin, float* __restrict__ cnew, uint16_t* __restrict__ S2t)
{
    __shared__ F1Sm s;
    int bid = blockIdx.x;
    fuse1_body(part, W, bb, cin, cnew, S2t, bid >> 7, (bid & 127) * 32, s, threadIdx.x);
}
__global__ __launch_bounds__(256) void fuse2_k(const float* __restrict__ part,
    const float* __restrict__ W, const float* __restrict__ bb,
    const float* __restrict__ mf, float* __restrict__ hnew, float* __restrict__ mnew)
{
    __shared__ F2Sm s;
    int bid = blockIdx.x;
    fuse2_body(part, W, bb, mf, hnew, mnew, bid >> 7, (bid & 127) * 32, s, threadIdx.x);
}

extern "C" void kernel_launch(void* const* d_in, const int* in_sizes, int n_in,
                              void* d_out, int out_size, void* d_ws, size_t ws_size,
                              hipStream_t stream) {
    (void)in_sizes; (void)n_in; (void)out_size;
    const float* x   = (const float*)d_in[0];
    const float* h   = (const float*)d_in[1];
    const float* c   = (const float*)d_in[2];
    const float* m   = (const float*)d_in[3];
    const float* adj = (const float*)d_in[4];
    const float* W   = (const float*)d_in[5];
    const float* bb  = (const float*)d_in[6];
    float* out = (float*)d_out;

    char* ws = (char*)d_ws;
    uint16_t* adjb = (uint16_t*)ws;                    // 32 MB bf16 adj
    uint16_t* P    = (uint16_t*)(ws + (32u << 20));    // 2 MB packed states
    float*    part = (float*)(ws + (34u << 20));       // 32 MB split-K partials
    if (ws_size < (size_t)(66u << 20)) return;         // ws known = 256 MB

    void* kargs[] = { (void*)&adj, (void*)&x, (void*)&h, (void*)&c, (void*)&m,
                      (void*)&W, (void*)&bb, (void*)&out, (void*)&adjb,
                      (void*)&P, (void*)&part };
    hipError_t e = hipLaunchCooperativeKernel((void*)mega_kernel, dim3(512), dim3(256),
                                              kargs, 0, stream);
    if (e == hipSuccess) return;

    // fallback: validated R7 multi-kernel pipeline
    cvt_adj_k<<<8192, 256, 0, stream>>>(adj, adjb);
    pack_k<<<512, 256, 0, stream>>>(x, h, P);
    gemm_k<<<dim3(32, 2, 8), 256, 0, stream>>>(adjb, P, part);
    fuse1_k<<<512, 256, 0, stream>>>(part, W, bb, c, out + BNF, P);
    pack_k<<<256, 256, 0, stream>>>(m, m, P + (size_t)128 * NN);
    gemm_k<<<dim3(32, 2, 8), 256, 0, stream>>>(adjb, P, part);
    fuse2_k<<<512, 256, 0, stream>>>(part, W, bb, m, out, out + 2 * BNF);
}

// Round 9
// 278.652 us; speedup vs baseline: 1.6988x; 1.6988x over previous
//
#include <hip/hip_runtime.h>
#include <stdint.h>

typedef __attribute__((ext_vector_type(4))) float f32x4;
typedef __attribute__((ext_vector_type(8))) short s16x8;

#define BB 4
#define NN 4096
#define FF 32
#define BNF (BB*NN*FF)   // 524288
#define LDP 76           // LDS row stride (bf16 units): 152B -> 16-row bank period

// ---------- helpers ----------
static __device__ __forceinline__ float bf2f(uint16_t u) {
    union { uint32_t i; float f; } v; v.i = ((uint32_t)u) << 16; return v.f;
}
static __device__ __forceinline__ uint16_t f2bf(float f) {
    union { float f; uint32_t i; } v; v.f = f;
    uint32_t r = v.i + 0x7FFFu + ((v.i >> 16) & 1u);
    return (uint16_t)(r >> 16);
}
static __device__ __forceinline__ float sig_acc(float x) { return 1.0f / (1.0f + expf(-x)); }
static __device__ __forceinline__ void atomAddF(float* p, float v) {
    __hip_atomic_fetch_add(p, v, __ATOMIC_RELAXED, __HIP_MEMORY_SCOPE_AGENT);
}

// ---------- pack: state [B][N][F] fp32 -> dst[rowBase + b*32 + f][n] bf16 ----------
__global__ __launch_bounds__(256) void pack_k(
    const float* __restrict__ s0, const float* __restrict__ s1,
    uint16_t* __restrict__ dst)
{
    __shared__ uint16_t tl[32][65];
    int bid = blockIdx.x;
    int tensor = bid >> 8;
    const float* src = tensor ? s1 : s0;
    int b = (bid >> 6) & 3, ntile = bid & 63;
    int rowBase = tensor * 128;
    int n0 = ntile * 64;
    int t = threadIdx.x;
    {
        int i = t >> 2, ch = t & 3;
        size_t idx = ((size_t)(b * NN + n0 + i)) * FF + ch * 8;
        float4 v0 = *(const float4*)(src + idx);
        float4 v1 = *(const float4*)(src + idx + 4);
        uint16_t e[8] = { f2bf(v0.x), f2bf(v0.y), f2bf(v0.z), f2bf(v0.w),
                          f2bf(v1.x), f2bf(v1.y), f2bf(v1.z), f2bf(v1.w) };
        #pragma unroll
        for (int k = 0; k < 8; k++) tl[ch * 8 + k][i] = e[k];
    }
    __syncthreads();
    {
        int f = t >> 3, ch = t & 7;
        union { uint4 u; uint16_t e[8]; } v;
        #pragma unroll
        for (int k = 0; k < 8; k++) v.e[k] = tl[f][ch * 8 + k];
        size_t row = (size_t)(rowBase + b * 32 + f);
        *(uint4*)(dst + row * NN + n0 + ch * 8) = v.u;
    }
}

// ---------- GEMM: Cf[m][c] += sum_k adj[m][k]*Bt[c][k]  (fp32 atomic epilogue) ----
// 128x128 tile, BK=64, 4 waves (2x2 of 64x64), padded LDS (no bank conflicts),
// register prefetch; A read directly as fp32 (cvt in reg).
__global__ __launch_bounds__(256) void gemm_k(
    const float* __restrict__ A,      // adj [4096][4096] fp32
    const uint16_t* __restrict__ Bt,  // [256][4096] bf16
    float* __restrict__ Cf,           // [4096][256] fp32, pre-zeroed
    int kLen)
{
    int mt = blockIdx.x, nt = blockIdx.y, ks = blockIdx.z;
    int m0 = mt * 128, c0 = nt * 128, k0 = ks * kLen;
    int kend = k0 + kLen;
    __shared__ __align__(16) uint16_t aL[128 * LDP];
    __shared__ __align__(16) uint16_t bL[128 * LDP];
    int t = threadIdx.x;
    int lane = t & 63, w = t >> 6;
    int wm = (w & 1) * 64, wn = (w >> 1) * 64;
    int lm = lane & 15, lk = lane >> 4;

    // staging map: 1024 chunks of 8 elems per tile; chunk q of thread t:
    // row = t&127, kcol8 = (t>>7) + 2q  (k-offset = kcol8*8)
    int srow = t & 127;
    int scol0 = t >> 7;

    f32x4 acc[4][4] = {};
    float4 pa[4][2];
    uint4 pb[4];

    // prologue loads (kk = k0)
    #pragma unroll
    for (int q = 0; q < 4; q++) {
        int kc = (scol0 + 2 * q) * 8;
        pa[q][0] = *(const float4*)(A + (size_t)(m0 + srow) * 4096 + k0 + kc);
        pa[q][1] = *(const float4*)(A + (size_t)(m0 + srow) * 4096 + k0 + kc + 4);
        pb[q]    = *(const uint4*)(Bt + (size_t)(c0 + srow) * 4096 + k0 + kc);
    }

    for (int kk = k0; kk < kend; kk += 64) {
        if (kk != k0) __syncthreads();
        #pragma unroll
        for (int q = 0; q < 4; q++) {
            int kc = (scol0 + 2 * q) * 8;
            union { uint4 u; uint16_t e[8]; } wa;
            wa.e[0] = f2bf(pa[q][0].x); wa.e[1] = f2bf(pa[q][0].y);
            wa.e[2] = f2bf(pa[q][0].z); wa.e[3] = f2bf(pa[q][0].w);
            wa.e[4] = f2bf(pa[q][1].x); wa.e[5] = f2bf(pa[q][1].y);
            wa.e[6] = f2bf(pa[q][1].z); wa.e[7] = f2bf(pa[q][1].w);
            *(uint4*)(aL + srow * LDP + kc) = wa.u;
            *(uint4*)(bL + srow * LDP + kc) = pb[q];
        }
        __syncthreads();

        int kn = kk + 64;
        if (kn < kend) {
            #pragma unroll
            for (int q = 0; q < 4; q++) {
                int kc = (scol0 + 2 * q) * 8;
                pa[q][0] = *(const float4*)(A + (size_t)(m0 + srow) * 4096 + kn + kc);
                pa[q][1] = *(const float4*)(A + (size_t)(m0 + srow) * 4096 + kn + kc + 4);
                pb[q]    = *(const uint4*)(Bt + (size_t)(c0 + srow) * 4096 + kn + kc);
            }
        }

        #pragma unroll
        for (int kh = 0; kh < 2; kh++) {
            s16x8 af[4], bfr[4];
            #pragma unroll
            for (int i = 0; i < 4; i++)
                af[i] = *(const s16x8*)(aL + (wm + i * 16 + lm) * LDP + kh * 32 + lk * 8);
            #pragma unroll
            for (int j = 0; j < 4; j++)
                bfr[j] = *(const s16x8*)(bL + (wn + j * 16 + lm) * LDP + kh * 32 + lk * 8);
            #pragma unroll
            for (int i = 0; i < 4; i++)
                #pragma unroll
                for (int j = 0; j < 4; j++)
                    acc[i][j] = __builtin_amdgcn_mfma_f32_16x16x32_bf16(af[i], bfr[j], acc[i][j], 0, 0, 0);
        }
    }

    // C/D layout: col(lane&15)->c, row((lane>>4)*4+reg)->m
    int r4 = (lane >> 4) * 4;
    #pragma unroll
    for (int i = 0; i < 4; i++)
        #pragma unroll
        for (int j = 0; j < 4; j++) {
            int c = c0 + wn + j * 16 + lm;
            int mrb = m0 + wm + i * 16 + r4;
            #pragma unroll
            for (int r = 0; r < 4; r++)
                atomAddF(&Cf[(size_t)(mrb + r) * 256 + c], acc[i][j][r]);
        }
}

// ---------- stage: Cf [m][c] fp32 -> AL[node][64] ----------
static __device__ __forceinline__ void stage_acts(
    const float* __restrict__ Cf, int b, int n0, int t, float AL[32][65])
{
    int node = t >> 3, q = t & 7;
    int fa0 = q * 8;
    int cb = (fa0 < 32) ? (b * 32 + fa0) : (128 + b * 32 + (fa0 - 32));
    const float* p = Cf + (size_t)(n0 + node) * 256 + cb;
    float4 v0 = *(const float4*)p;
    float4 v1 = *(const float4*)(p + 4);
    AL[node][fa0 + 0] = v0.x; AL[node][fa0 + 1] = v0.y;
    AL[node][fa0 + 2] = v0.z; AL[node][fa0 + 3] = v0.w;
    AL[node][fa0 + 4] = v1.x; AL[node][fa0 + 5] = v1.y;
    AL[node][fa0 + 6] = v1.z; AL[node][fa0 + 7] = v1.w;
}

// ---------- fuse1: 8-gate GLU + LSTM; c_new (fp32) + packed h1 (bf16) ----------
__global__ __launch_bounds__(256) void fuse1_k(
    const float* __restrict__ Cf, const float* __restrict__ Wf,
    const float* __restrict__ bf_, const float* __restrict__ cf,
    float* __restrict__ cnew, uint16_t* __restrict__ S2t)
{
    __shared__ uint32_t WL[8192];
    __shared__ float BL[512];
    __shared__ float AL[32][65];
    __shared__ uint16_t H1[32][33];

    int t = threadIdx.x;
    int bid = blockIdx.x;
    int b = bid >> 7, n0 = (bid & 127) * 32;

    for (int i = t; i < 8192; i += 256) {
        int g = i >> 10, rem = i & 1023, f = rem >> 5, j = rem & 31;
        uint32_t lo = f2bf(Wf[g * 2048 + f * 64 + j]);
        uint32_t hi = f2bf(Wf[g * 2048 + f * 64 + 32 + j]);
        WL[i] = lo | (hi << 16);
    }
    if (t < 128) {
        #pragma unroll
        for (int k = 0; k < 4; k++) BL[t * 4 + k] = bf_[t * 4 + k];
    }
    stage_acts(Cf, b, n0, t, AL);
    __syncthreads();

    int j = t & 31, nb = t >> 5;
    float acc[4][16];
    #pragma unroll
    for (int u = 0; u < 4; u++)
        #pragma unroll
        for (int g = 0; g < 8; g++) {
            acc[u][g * 2]     = BL[g * 64 + j];
            acc[u][g * 2 + 1] = BL[g * 64 + 32 + j];
        }
    #pragma unroll 2
    for (int f = 0; f < 32; f++) {
        float wls[8], wrs[8];
        #pragma unroll
        for (int g = 0; g < 8; g++) {
            uint32_t wv = WL[g * 1024 + f * 32 + j];
            wls[g] = __uint_as_float(wv << 16);
            wrs[g] = __uint_as_float(wv & 0xFFFF0000u);
        }
        #pragma unroll
        for (int u = 0; u < 4; u++) {
            int node = nb + u * 8;
            float ax = AL[node][f], ah = AL[node][32 + f];
            #pragma unroll
            for (int g = 0; g < 8; g++) {
                float src = (g & 1) ? ah : ax;
                acc[u][g * 2]     += src * wls[g];
                acc[u][g * 2 + 1] += src * wrs[g];
            }
        }
    }
    #pragma unroll
    for (int u = 0; u < 4; u++) {
        int node = nb + u * 8;
        float fx = acc[u][0]  * sig_acc(acc[u][1]);
        float fh = acc[u][2]  * sig_acc(acc[u][3]);
        float ix = acc[u][4]  * sig_acc(acc[u][5]);
        float ih = acc[u][6]  * sig_acc(acc[u][7]);
        float cx = acc[u][8]  * sig_acc(acc[u][9]);
        float ch = acc[u][10] * sig_acc(acc[u][11]);
        float ox = acc[u][12] * sig_acc(acc[u][13]);
        float oh = acc[u][14] * sig_acc(acc[u][15]);
        float fg = sig_acc(fx + fh), ig = sig_acc(ix + ih), og = sig_acc(ox + oh);
        size_t gidx = ((size_t)(b * NN + n0 + node)) * FF + j;
        float cvv = cf[gidx];
        float cn = fg * cvv + ig * tanhf(cx + ch);
        float h1 = og * tanhf(cn);
        cnew[gidx] = cn;
        H1[j][node] = f2bf(h1);
    }
    __syncthreads();
    {
        int fr = t >> 3, ch = t & 7;
        union { uint2 u; uint16_t e[4]; } v;
        #pragma unroll
        for (int k = 0; k < 4; k++) v.e[k] = H1[fr][ch * 4 + k];
        *(uint2*)(S2t + ((size_t)(b * 32 + fr)) * NN + n0 + ch * 4) = v.u;
    }
}

// ---------- fuse2: 6-gate GLU + memory-state; h_new, m_new (fp32) ----------
__global__ __launch_bounds__(256) void fuse2_k(
    const float* __restrict__ Cf, const float* __restrict__ Wf,
    const float* __restrict__ bf_, const float* __restrict__ mf,
    float* __restrict__ hnew, float* __restrict__ mnew)
{
    __shared__ uint32_t WL[6144];
    __shared__ float BL[384];
    __shared__ float AL[32][65];

    int t = threadIdx.x;
    int bid = blockIdx.x;
    int b = bid >> 7, n0 = (bid & 127) * 32;

    for (int i = t; i < 6144; i += 256) {
        int g = i >> 10, rem = i & 1023, f = rem >> 5, j = rem & 31;
        int gg = 8 + g;
        uint32_t lo = f2bf(Wf[gg * 2048 + f * 64 + j]);
        uint32_t hi = f2bf(Wf[gg * 2048 + f * 64 + 32 + j]);
        WL[i] = lo | (hi << 16);
    }
    if (t < 96) {
        #pragma unroll
        for (int k = 0; k < 4; k++) BL[t * 4 + k] = bf_[512 + t * 4 + k];
    }
    stage_acts(Cf, b, n0, t, AL);
    __syncthreads();

    int j = t & 31, nb = t >> 5;
    float acc[4][12];
    #pragma unroll
    for (int u = 0; u < 4; u++)
        #pragma unroll
        for (int g = 0; g < 6; g++) {
            acc[u][g * 2]     = BL[g * 64 + j];
            acc[u][g * 2 + 1] = BL[g * 64 + 32 + j];
        }
    #pragma unroll 2
    for (int f = 0; f < 32; f++) {
        float wls[6], wrs[6];
        #pragma unroll
        for (int g = 0; g < 6; g++) {
            uint32_t wv = WL[g * 1024 + f * 32 + j];
            wls[g] = __uint_as_float(wv << 16);
            wrs[g] = __uint_as_float(wv & 0xFFFF0000u);
        }
        #pragma unroll
        for (int u = 0; u < 4; u++) {
            int node = nb + u * 8;
            float ah1 = AL[node][f], am = AL[node][32 + f];
            #pragma unroll
            for (int g = 0; g < 6; g++) {
                float src = (g & 1) ? am : ah1;
                acc[u][g * 2]     += src * wls[g];
                acc[u][g * 2 + 1] += src * wrs[g];
            }
        }
    }
    #pragma unroll
    for (int u = 0; u < 4; u++) {
        int node = nb + u * 8;
        float sa_ih = acc[u][0]  * sig_acc(acc[u][1]);
        float sa_im = acc[u][2]  * sig_acc(acc[u][3]);
        float sa_gh = acc[u][4]  * sig_acc(acc[u][5]);
        float sa_gm = acc[u][6]  * sig_acc(acc[u][7]);
        float sa_oh = acc[u][8]  * sig_acc(acc[u][9]);
        float sa_om = acc[u][10] * sig_acc(acc[u][11]);
        float i2 = sig_acc(sa_ih + sa_im);
        float g2 = sig_acc(sa_gh + sa_gm);
        float o2 = sig_acc(sa_oh + sa_om);
        size_t gidx = ((size_t)(b * NN + n0 + node)) * FF + j;
        float mvv = mf[gidx];
        float mn = i2 * mvv + (1.0f - i2) * g2;
        float hn = mn * o2;
        mnew[gidx] = mn;
        hnew[gidx] = hn;
    }
}

extern "C" void kernel_launch(void* const* d_in, const int* in_sizes, int n_in,
                              void* d_out, int out_size, void* d_ws, size_t ws_size,
                              hipStream_t stream) {
    (void)in_sizes; (void)n_in; (void)out_size;
    const float* x   = (const float*)d_in[0];
    const float* h   = (const float*)d_in[1];
    const float* c   = (const float*)d_in[2];
    const float* m   = (const float*)d_in[3];
    const float* adj = (const float*)d_in[4];
    const float* W   = (const float*)d_in[5];
    const float* bb  = (const float*)d_in[6];
    float* out = (float*)d_out;

    char* ws = (char*)d_ws;
    uint16_t* P   = (uint16_t*)ws;                    // 2 MB packed states
    float*    C1f = (float*)(ws + (2u << 20));        // 4 MB  adj@[x|h]
    float*    C2f = (float*)(ws + (6u << 20));        // 4 MB  adj@[h1|m]
    if (ws_size < (size_t)(10u << 20)) return;

    hipMemsetAsync(C1f, 0, (size_t)(4u << 20), stream);
    hipMemsetAsync(C2f, 0, (size_t)(4u << 20), stream);

    pack_k<<<512, 256, 0, stream>>>(x, h, P);
    gemm_k<<<dim3(32, 2, 8), 256, 0, stream>>>(adj, P, C1f, 512);
    fuse1_k<<<512, 256, 0, stream>>>(C1f, W, bb, c, out + BNF, P);
    pack_k<<<256, 256, 0, stream>>>(m, m, P + (size_t)128 * NN);
    gemm_k<<<dim3(32, 2, 8), 256, 0, stream>>>(adj, P, C2f, 512);
    fuse2_k<<<512, 256, 0, stream>>>(C2f, W, bb, m, out, out + 2 * BNF);
}

// Round 10
// 257.200 us; speedup vs baseline: 1.8405x; 1.0834x over previous
//
#include <hip/hip_runtime.h>
#include <stdint.h>

typedef __attribute__((ext_vector_type(4))) float f32x4;
typedef __attribute__((ext_vector_type(8))) short s16x8;

#define BB 4
#define NN 4096
#define FF 32
#define BNF (BB*NN*FF)   // 524288
#define LDP 72           // LDS row stride (bf16): 144B; frag reads <=2-way (free)

// ---------- helpers ----------
static __device__ __forceinline__ float bf2f(uint16_t u) {
    union { uint32_t i; float f; } v; v.i = ((uint32_t)u) << 16; return v.f;
}
static __device__ __forceinline__ uint16_t f2bf(float f) {
    union { float f; uint32_t i; } v; v.f = f;
    uint32_t r = v.i + 0x7FFFu + ((v.i >> 16) & 1u);
    return (uint16_t)(r >> 16);
}
static __device__ __forceinline__ float sig_acc(float x) { return 1.0f / (1.0f + expf(-x)); }

// ---------- pack: x,h -> P1 rows 0..255; m -> P2 rows 128..255 (bf16, [row][n]) ----
__global__ __launch_bounds__(256) void pack_k(
    const float* __restrict__ x, const float* __restrict__ h,
    const float* __restrict__ m, uint16_t* __restrict__ P1,
    uint16_t* __restrict__ P2)
{
    __shared__ uint16_t tl[32][65];
    int bid = blockIdx.x;
    int tensor = bid >> 8;                     // 0:x 1:h 2:m
    const float* src = (tensor == 0) ? x : (tensor == 1) ? h : m;
    uint16_t* dst = (tensor == 2) ? (P2 + (size_t)128 * NN) : (P1 + (size_t)tensor * 128 * NN);
    int b = (bid >> 6) & 3, ntile = bid & 63;
    int n0 = ntile * 64;
    int t = threadIdx.x;
    {
        int i = t >> 2, ch = t & 3;
        size_t idx = ((size_t)(b * NN + n0 + i)) * FF + ch * 8;
        float4 v0 = *(const float4*)(src + idx);
        float4 v1 = *(const float4*)(src + idx + 4);
        uint16_t e[8] = { f2bf(v0.x), f2bf(v0.y), f2bf(v0.z), f2bf(v0.w),
                          f2bf(v1.x), f2bf(v1.y), f2bf(v1.z), f2bf(v1.w) };
        #pragma unroll
        for (int k = 0; k < 8; k++) tl[ch * 8 + k][i] = e[k];
    }
    __syncthreads();
    {
        int f = t >> 3, ch = t & 7;
        union { uint4 u; uint16_t e[8]; } v;
        #pragma unroll
        for (int k = 0; k < 8; k++) v.e[k] = tl[f][ch * 8 + k];
        *(uint4*)(dst + ((size_t)(b * 32 + f)) * NN + n0 + ch * 8) = v.u;
    }
}

// ---------- GEMM: part[ks][m][c] = sum_k adj[m][k]*Bt[c][k] over K-split ----------
// 64x128 tile, BK=64, grid (64,2,8) = 1024 blocks (4/CU), padded LDS,
// fp32-A direct staging (cvt in reg), register prefetch.
__global__ __launch_bounds__(256, 4) void gemm_k(
    const float* __restrict__ A,      // adj [4096][4096] fp32
    const uint16_t* __restrict__ Bt,  // [256][4096] bf16
    float* __restrict__ part)         // [8][4096][256] fp32
{
    int mt = blockIdx.x, nt = blockIdx.y, ks = blockIdx.z;
    int m0 = mt * 64, c0 = nt * 128, k0 = ks * 512;
    int kend = k0 + 512;
    __shared__ __align__(16) uint16_t aL[64 * LDP];
    __shared__ __align__(16) uint16_t bL[128 * LDP];
    int t = threadIdx.x;
    int lane = t & 63, w = t >> 6;
    int wm = (w & 1) * 32, wn = (w >> 1) * 64;
    int lm = lane & 15, lk = lane >> 4;

    // staging: A 64x64 (512 chunks of 8, 2/thread), B 128x64 (1024 chunks, 4/thread)
    int arow[2], akc[2], brow[4], bkc[4];
    #pragma unroll
    for (int q = 0; q < 2; q++) { int id = q * 256 + t; arow[q] = id >> 3; akc[q] = (id & 7) * 8; }
    #pragma unroll
    for (int q = 0; q < 4; q++) { int id = q * 256 + t; brow[q] = id >> 3; bkc[q] = (id & 7) * 8; }

    f32x4 acc[2][4] = {};
    float4 pa[2][2];
    uint4 pb[4];

    #pragma unroll
    for (int q = 0; q < 2; q++) {
        const float* p = A + (size_t)(m0 + arow[q]) * 4096 + k0 + akc[q];
        pa[q][0] = *(const float4*)p;
        pa[q][1] = *(const float4*)(p + 4);
    }
    #pragma unroll
    for (int q = 0; q < 4; q++)
        pb[q] = *(const uint4*)(Bt + (size_t)(c0 + brow[q]) * 4096 + k0 + bkc[q]);

    for (int kk = k0; kk < kend; kk += 64) {
        if (kk != k0) __syncthreads();
        #pragma unroll
        for (int q = 0; q < 2; q++) {
            union { uint4 u; uint16_t e[8]; } wa;
            wa.e[0] = f2bf(pa[q][0].x); wa.e[1] = f2bf(pa[q][0].y);
            wa.e[2] = f2bf(pa[q][0].z); wa.e[3] = f2bf(pa[q][0].w);
            wa.e[4] = f2bf(pa[q][1].x); wa.e[5] = f2bf(pa[q][1].y);
            wa.e[6] = f2bf(pa[q][1].z); wa.e[7] = f2bf(pa[q][1].w);
            *(uint4*)(aL + arow[q] * LDP + akc[q]) = wa.u;
        }
        #pragma unroll
        for (int q = 0; q < 4; q++)
            *(uint4*)(bL + brow[q] * LDP + bkc[q]) = pb[q];
        __syncthreads();

        int kn = kk + 64;
        if (kn < kend) {
            #pragma unroll
            for (int q = 0; q < 2; q++) {
                const float* p = A + (size_t)(m0 + arow[q]) * 4096 + kn + akc[q];
                pa[q][0] = *(const float4*)p;
                pa[q][1] = *(const float4*)(p + 4);
            }
            #pragma unroll
            for (int q = 0; q < 4; q++)
                pb[q] = *(const uint4*)(Bt + (size_t)(c0 + brow[q]) * 4096 + kn + bkc[q]);
        }

        #pragma unroll
        for (int kh = 0; kh < 2; kh++) {
            s16x8 af[2], bfr[4];
            #pragma unroll
            for (int i = 0; i < 2; i++)
                af[i] = *(const s16x8*)(aL + (wm + i * 16 + lm) * LDP + kh * 32 + lk * 8);
            #pragma unroll
            for (int j = 0; j < 4; j++)
                bfr[j] = *(const s16x8*)(bL + (wn + j * 16 + lm) * LDP + kh * 32 + lk * 8);
            #pragma unroll
            for (int i = 0; i < 2; i++)
                #pragma unroll
                for (int j = 0; j < 4; j++)
                    acc[i][j] = __builtin_amdgcn_mfma_f32_16x16x32_bf16(af[i], bfr[j], acc[i][j], 0, 0, 0);
        }
    }

    // C/D: col(lane&15)->c, row((lane>>4)*4+reg)->m; [m][c] coalesced in c
    int r4 = (lane >> 4) * 4;
    #pragma unroll
    for (int i = 0; i < 2; i++)
        #pragma unroll
        for (int j = 0; j < 4; j++) {
            int c = c0 + wn + j * 16 + lm;
            int mrb = m0 + wm + i * 16 + r4;
            #pragma unroll
            for (int r = 0; r < 4; r++)
                part[((size_t)blockIdx.z * 4096 + mrb + r) * 256 + c] = acc[i][j][r];
        }
}

// ---------- stage: sum 8 split-K partials [ks][m][c] -> AL[node][64] ----------
static __device__ __forceinline__ void stage_acts8(
    const float* __restrict__ part, int b, int n0, int t, float AL[32][65])
{
    int node = t >> 3, q = t & 7;
    int fa0 = q * 8;
    int cb = (fa0 < 32) ? (b * 32 + fa0) : (128 + b * 32 + (fa0 - 32));
    float s[8] = {};
    #pragma unroll
    for (int k = 0; k < 8; k++) {
        const float* p = part + ((size_t)k * 4096 + n0 + node) * 256 + cb;
        float4 v0 = *(const float4*)p;
        float4 v1 = *(const float4*)(p + 4);
        s[0] += v0.x; s[1] += v0.y; s[2] += v0.z; s[3] += v0.w;
        s[4] += v1.x; s[5] += v1.y; s[6] += v1.z; s[7] += v1.w;
    }
    #pragma unroll
    for (int k = 0; k < 8; k++) AL[node][fa0 + k] = s[k];
}

// ---------- fuse1: 8-gate GLU + LSTM; c_new (fp32) + packed h1 -> P2 rows 0..127 ----
__global__ __launch_bounds__(256) void fuse1_k(
    const float* __restrict__ part, const float* __restrict__ Wf,
    const float* __restrict__ bf_, const float* __restrict__ cf,
    float* __restrict__ cnew, uint16_t* __restrict__ S2t)
{
    __shared__ uint32_t WL[8192];
    __shared__ float BL[512];
    __shared__ float AL[32][65];
    __shared__ uint16_t H1[32][33];

    int t = threadIdx.x;
    int bid = blockIdx.x;
    int b = bid >> 7, n0 = (bid & 127) * 32;

    for (int i = t; i < 8192; i += 256) {
        int g = i >> 10, rem = i & 1023, f = rem >> 5, j = rem & 31;
        uint32_t lo = f2bf(Wf[g * 2048 + f * 64 + j]);
        uint32_t hi = f2bf(Wf[g * 2048 + f * 64 + 32 + j]);
        WL[i] = lo | (hi << 16);
    }
    if (t < 128) {
        #pragma unroll
        for (int k = 0; k < 4; k++) BL[t * 4 + k] = bf_[t * 4 + k];
    }
    stage_acts8(part, b, n0, t, AL);
    __syncthreads();

    int j = t & 31, nb = t >> 5;
    float acc[4][16];
    #pragma unroll
    for (int u = 0; u < 4; u++)
        #pragma unroll
        for (int g = 0; g < 8; g++) {
            acc[u][g * 2]     = BL[g * 64 + j];
            acc[u][g * 2 + 1] = BL[g * 64 + 32 + j];
        }
    #pragma unroll 2
    for (int f = 0; f < 32; f++) {
        float wls[8], wrs[8];
        #pragma unroll
        for (int g = 0; g < 8; g++) {
            uint32_t wv = WL[g * 1024 + f * 32 + j];
            wls[g] = __uint_as_float(wv << 16);
            wrs[g] = __uint_as_float(wv & 0xFFFF0000u);
        }
        #pragma unroll
        for (int u = 0; u < 4; u++) {
            int node = nb + u * 8;
            float ax = AL[node][f], ah = AL[node][32 + f];
            #pragma unroll
            for (int g = 0; g < 8; g++) {
                float src = (g & 1) ? ah : ax;
                acc[u][g * 2]     += src * wls[g];
                acc[u][g * 2 + 1] += src * wrs[g];
            }
        }
    }
    #pragma unroll
    for (int u = 0; u < 4; u++) {
        int node = nb + u * 8;
        float fx = acc[u][0]  * sig_acc(acc[u][1]);
        float fh = acc[u][2]  * sig_acc(acc[u][3]);
        float ix = acc[u][4]  * sig_acc(acc[u][5]);
        float ih = acc[u][6]  * sig_acc(acc[u][7]);
        float cx = acc[u][8]  * sig_acc(acc[u][9]);
        float ch = acc[u][10] * sig_acc(acc[u][11]);
        float ox = acc[u][12] * sig_acc(acc[u][13]);
        float oh = acc[u][14] * sig_acc(acc[u][15]);
        float fg = sig_acc(fx + fh), ig = sig_acc(ix + ih), og = sig_acc(ox + oh);
        size_t gidx = ((size_t)(b * NN + n0 + node)) * FF + j;
        float cvv = cf[gidx];
        float cn = fg * cvv + ig * tanhf(cx + ch);
        float h1 = og * tanhf(cn);
        cnew[gidx] = cn;
        H1[j][node] = f2bf(h1);
    }
    __syncthreads();
    {
        int fr = t >> 3, ch = t & 7;
        union { uint2 u; uint16_t e[4]; } v;
        #pragma unroll
        for (int k = 0; k < 4; k++) v.e[k] = H1[fr][ch * 4 + k];
        *(uint2*)(S2t + ((size_t)(b * 32 + fr)) * NN + n0 + ch * 4) = v.u;
    }
}

// ---------- fuse2: 6-gate GLU + memory-state; h_new, m_new (fp32) ----------
__global__ __launch_bounds__(256) void fuse2_k(
    const float* __restrict__ part, const float* __restrict__ Wf,
    const float* __restrict__ bf_, const float* __restrict__ mf,
    float* __restrict__ hnew, float* __restrict__ mnew)
{
    __shared__ uint32_t WL[6144];
    __shared__ float BL[384];
    __shared__ float AL[32][65];

    int t = threadIdx.x;
    int bid = blockIdx.x;
    int b = bid >> 7, n0 = (bid & 127) * 32;

    for (int i = t; i < 6144; i += 256) {
        int g = i >> 10, rem = i & 1023, f = rem >> 5, j = rem & 31;
        int gg = 8 + g;
        uint32_t lo = f2bf(Wf[gg * 2048 + f * 64 + j]);
        uint32_t hi = f2bf(Wf[gg * 2048 + f * 64 + 32 + j]);
        WL[i] = lo | (hi << 16);
    }
    if (t < 96) {
        #pragma unroll
        for (int k = 0; k < 4; k++) BL[t * 4 + k] = bf_[512 + t * 4 + k];
    }
    stage_acts8(part, b, n0, t, AL);
    __syncthreads();

    int j = t & 31, nb = t >> 5;
    float acc[4][12];
    #pragma unroll
    for (int u = 0; u < 4; u++)
        #pragma unroll
        for (int g = 0; g < 6; g++) {
            acc[u][g * 2]     = BL[g * 64 + j];
            acc[u][g * 2 + 1] = BL[g * 64 + 32 + j];
        }
    #pragma unroll 2
    for (int f = 0; f < 32; f++) {
        float wls[6], wrs[6];
        #pragma unroll
        for (int g = 0; g < 6; g++) {
            uint32_t wv = WL[g * 1024 + f * 32 + j];
            wls[g] = __uint_as_float(wv << 16);
            wrs[g] = __uint_as_float(wv & 0xFFFF0000u);
        }
        #pragma unroll
        for (int u = 0; u < 4; u++) {
            int node = nb + u * 8;
            float ah1 = AL[node][f], am = AL[node][32 + f];
            #pragma unroll
            for (int g = 0; g < 6; g++) {
                float src = (g & 1) ? am : ah1;
                acc[u][g * 2]     += src * wls[g];
                acc[u][g * 2 + 1] += src * wrs[g];
            }
        }
    }
    #pragma unroll
    for (int u = 0; u < 4; u++) {
        int node = nb + u * 8;
        float sa_ih = acc[u][0]  * sig_acc(acc[u][1]);
        float sa_im = acc[u][2]  * sig_acc(acc[u][3]);
        float sa_gh = acc[u][4]  * sig_acc(acc[u][5]);
        float sa_gm = acc[u][6]  * sig_acc(acc[u][7]);
        float sa_oh = acc[u][8]  * sig_acc(acc[u][9]);
        float sa_om = acc[u][10] * sig_acc(acc[u][11]);
        float i2 = sig_acc(sa_ih + sa_im);
        float g2 = sig_acc(sa_gh + sa_gm);
        float o2 = sig_acc(sa_oh + sa_om);
        size_t gidx = ((size_t)(b * NN + n0 + node)) * FF + j;
        float mvv = mf[gidx];
        float mn = i2 * mvv + (1.0f - i2) * g2;
        float hn = mn * o2;
        mnew[gidx] = mn;
        hnew[gidx] = hn;
    }
}

extern "C" void kernel_launch(void* const* d_in, const int* in_sizes, int n_in,
                              void* d_out, int out_size, void* d_ws, size_t ws_size,
                              hipStream_t stream) {
    (void)in_sizes; (void)n_in; (void)out_size;
    const float* x   = (const float*)d_in[0];
    const float* h   = (const float*)d_in[1];
    const float* c   = (const float*)d_in[2];
    const float* m   = (const float*)d_in[3];
    const float* adj = (const float*)d_in[4];
    const float* W   = (const float*)d_in[5];
    const float* bb  = (const float*)d_in[6];
    float* out = (float*)d_out;

    char* ws = (char*)d_ws;
    uint16_t* P1   = (uint16_t*)ws;                   // 2 MB  [x|h] packed
    uint16_t* P2   = (uint16_t*)(ws + (2u << 20));    // 2 MB  [h1|m] packed
    float*    part = (float*)(ws + (4u << 20));       // 32 MB split-K partials
    if (ws_size < (size_t)(36u << 20)) return;

    // 5 dispatches total (~10us/dispatch graph-node overhead measured R5/R6/R9)
    pack_k<<<768, 256, 0, stream>>>(x, h, m, P1, P2);
    gemm_k<<<dim3(64, 2, 8), 256, 0, stream>>>(adj, P1, part);
    fuse1_k<<<512, 256, 0, stream>>>(part, W, bb, c, out + BNF, P2);
    gemm_k<<<dim3(64, 2, 8), 256, 0, stream>>>(adj, P2, part);
    fuse2_k<<<512, 256, 0, stream>>>(part, W, bb, m, out, out + 2 * BNF);
}

// Round 11
// 211.654 us; speedup vs baseline: 2.2366x; 1.2152x over previous
//
#include <hip/hip_runtime.h>
#include <stdint.h>

typedef __attribute__((ext_vector_type(4))) float f32x4;
typedef __attribute__((ext_vector_type(8))) short s16x8;

#define BB 4
#define NN 4096
#define FF 32
#define BNF (BB*NN*FF)   // 524288

// ---------- helpers ----------
static __device__ __forceinline__ float bf2f(uint16_t u) {
    union { uint32_t i; float f; } v; v.i = ((uint32_t)u) << 16; return v.f;
}
static __device__ __forceinline__ uint16_t f2bf(float f) {
    union { float f; uint32_t i; } v; v.f = f;
    uint32_t r = v.i + 0x7FFFu + ((v.i >> 16) & 1u);
    return (uint16_t)(r >> 16);
}
static __device__ __forceinline__ float sig_acc(float x) { return 1.0f / (1.0f + expf(-x)); }

typedef __attribute__((address_space(1))) const uint32_t glds_src_t;
typedef __attribute__((address_space(3))) uint32_t glds_dst_t;
static __device__ __forceinline__ void async_copy16(const void* g, void* l) {
    __builtin_amdgcn_global_load_lds((glds_src_t*)g, (glds_dst_t*)l, 16, 0, 0);
}

// ---------- prep: adj fp32->bf16 (blocks 768..8959) + pack x,h,m (blocks 0..767) ----
__global__ __launch_bounds__(256) void prep_k(
    const float* __restrict__ x, const float* __restrict__ h,
    const float* __restrict__ m, const float* __restrict__ adj,
    uint16_t* __restrict__ P1, uint16_t* __restrict__ adjb)
{
    __shared__ uint16_t tl[32][65];
    int bid = blockIdx.x;
    int t = threadIdx.x;
    if (bid >= 768) {
        size_t i = ((size_t)(bid - 768) * 256 + t) * 8;
        float4 v0 = *(const float4*)(adj + i);
        float4 v1 = *(const float4*)(adj + i + 4);
        union { uint4 u; uint16_t e[8]; } o;
        o.e[0] = f2bf(v0.x); o.e[1] = f2bf(v0.y); o.e[2] = f2bf(v0.z); o.e[3] = f2bf(v0.w);
        o.e[4] = f2bf(v1.x); o.e[5] = f2bf(v1.y); o.e[6] = f2bf(v1.z); o.e[7] = f2bf(v1.w);
        *(uint4*)(adjb + i) = o.u;
        return;
    }
    int tensor = bid >> 8;                     // 0:x 1:h 2:m -> P1 rows tensor*128..
    const float* src = (tensor == 0) ? x : (tensor == 1) ? h : m;
    int b = (bid >> 6) & 3, ntile = bid & 63;
    int n0 = ntile * 64;
    {
        int i = t >> 2, ch = t & 3;
        size_t idx = ((size_t)(b * NN + n0 + i)) * FF + ch * 8;
        float4 v0 = *(const float4*)(src + idx);
        float4 v1 = *(const float4*)(src + idx + 4);
        uint16_t e[8] = { f2bf(v0.x), f2bf(v0.y), f2bf(v0.z), f2bf(v0.w),
                          f2bf(v1.x), f2bf(v1.y), f2bf(v1.z), f2bf(v1.w) };
        #pragma unroll
        for (int k = 0; k < 8; k++) tl[ch * 8 + k][i] = e[k];
    }
    __syncthreads();
    {
        int f = t >> 3, ch = t & 7;
        union { uint4 u; uint16_t e[8]; } v;
        #pragma unroll
        for (int k = 0; k < 8; k++) v.e[k] = tl[f][ch * 8 + k];
        *(uint4*)(P1 + ((size_t)(tensor * 128 + b * 32 + f)) * NN + n0 + ch * 8) = v.u;
    }
}

// ---------- GEMM: part[ks][m][c] = sum_k adjb[m][k]*Bt[c][k] over K-split ----------
// 64x128 tile, BK=32, global_load_lds width-16 staging (m97 pattern), unpadded LDS.
__global__ __launch_bounds__(256) void gemm_k(
    const uint16_t* __restrict__ A16,  // adjb [4096][4096] bf16
    const uint16_t* __restrict__ Bt,   // [cw][4096] bf16
    float* __restrict__ part,          // [ns][4096][cw] fp32
    int cw, int kLen)
{
    int mt = blockIdx.x, nt = blockIdx.y, ks = blockIdx.z;
    int m0 = mt * 64, c0 = nt * 128, k0 = ks * kLen;
    int kend = k0 + kLen;
    __shared__ __align__(16) uint16_t aL[64 * 32];    // 4 KB
    __shared__ __align__(16) uint16_t bL[128 * 32];   // 8 KB
    int t = threadIdx.x;
    int lane = t & 63, w = t >> 6;
    int wm = (w & 1) * 32, wn = (w >> 1) * 64;
    int lm = lane & 15, lk = lane >> 4;

    // global_load_lds contract: lane i lands at waveBase + i*16B.
    // lane i covers row (i>>2), 16B chunk (i&3): offset = (i>>2)*64 + (i&3)*16 = i*16 ✓
    int arow = w * 16 + (lane >> 2);            // A rows w*16..w*16+15
    int brow0 = w * 16 + (lane >> 2);           // B chunk w
    int brow1 = (w + 4) * 16 + (lane >> 2);     // B chunk w+4
    int akc = (lane & 3) * 8;                   // k-offset (elems)
    uint16_t* aBase  = aL + w * 512;
    uint16_t* bBase0 = bL + w * 512;
    uint16_t* bBase1 = bL + (w + 4) * 512;

    f32x4 acc[2][4] = {};

    for (int kk = k0; kk < kend; kk += 32) {
        async_copy16(A16 + (size_t)(m0 + arow) * 4096 + kk + akc, aBase);
        async_copy16(Bt + (size_t)(c0 + brow0) * 4096 + kk + akc, bBase0);
        async_copy16(Bt + (size_t)(c0 + brow1) * 4096 + kk + akc, bBase1);
        __syncthreads();                         // drains vmcnt (loads done)
        s16x8 af[2], bfr[4];
        #pragma unroll
        for (int i = 0; i < 2; i++)
            af[i] = *(const s16x8*)(aL + (wm + i * 16 + lm) * 32 + lk * 8);
        #pragma unroll
        for (int j = 0; j < 4; j++)
            bfr[j] = *(const s16x8*)(bL + (wn + j * 16 + lm) * 32 + lk * 8);
        #pragma unroll
        for (int i = 0; i < 2; i++)
            #pragma unroll
            for (int j = 0; j < 4; j++)
                acc[i][j] = __builtin_amdgcn_mfma_f32_16x16x32_bf16(af[i], bfr[j], acc[i][j], 0, 0, 0);
        __syncthreads();                         // protect LDS before next overwrite
    }

    // C/D: col(lane&15)->c, row((lane>>4)*4+reg)->m; [m][c] store, c-coalesced
    int r4 = (lane >> 4) * 4;
    #pragma unroll
    for (int i = 0; i < 2; i++)
        #pragma unroll
        for (int j = 0; j < 4; j++) {
            int c = c0 + wn + j * 16 + lm;
            int mrb = m0 + wm + i * 16 + r4;
            #pragma unroll
            for (int r = 0; r < 4; r++)
                part[((size_t)ks * 4096 + mrb + r) * cw + c] = acc[i][j][r];
        }
}

// ---------- stage: sum split-K partials into AL[node][64]; two sources ----------
static __device__ __forceinline__ void stage_mixed(
    const float* __restrict__ pA, int cwA, int nsA, int cbA,
    const float* __restrict__ pB, int cwB, int nsB, int cbB,
    int n0, int t, float AL[32][65])
{
    int node = t >> 3, q = t & 7;
    int fa0 = q * 8;
    int first = fa0 < 32;
    const float* p0 = first ? pA : pB;
    int cw = first ? cwA : cwB;
    int ns = first ? nsA : nsB;
    int cb = first ? (cbA + fa0) : (cbB + fa0 - 32);
    float s[8] = {};
    for (int k = 0; k < ns; k++) {
        const float* p = p0 + ((size_t)k * 4096 + n0 + node) * cw + cb;
        float4 v0 = *(const float4*)p;
        float4 v1 = *(const float4*)(p + 4);
        s[0] += v0.x; s[1] += v0.y; s[2] += v0.z; s[3] += v0.w;
        s[4] += v1.x; s[5] += v1.y; s[6] += v1.z; s[7] += v1.w;
    }
    #pragma unroll
    for (int k = 0; k < 8; k++) AL[node][fa0 + k] = s[k];
}

// ---------- fuse1: 8-gate GLU + LSTM; c_new (fp32) + packed h1 -> P2 ----------
__global__ __launch_bounds__(256) void fuse1_k(
    const float* __restrict__ part1, const float* __restrict__ Wf,
    const float* __restrict__ bf_, const float* __restrict__ cf,
    float* __restrict__ cnew, uint16_t* __restrict__ P2)
{
    __shared__ uint32_t WL[8192];
    __shared__ float BL[512];
    __shared__ float AL[32][65];
    __shared__ uint16_t H1[32][33];

    int t = threadIdx.x;
    int bid = blockIdx.x;
    int b = bid >> 7, n0 = (bid & 127) * 32;

    for (int i = t; i < 8192; i += 256) {
        int g = i >> 10, rem = i & 1023, f = rem >> 5, j = rem & 31;
        uint32_t lo = f2bf(Wf[g * 2048 + f * 64 + j]);
        uint32_t hi = f2bf(Wf[g * 2048 + f * 64 + 32 + j]);
        WL[i] = lo | (hi << 16);
    }
    if (t < 128) {
        #pragma unroll
        for (int k = 0; k < 4; k++) BL[t * 4 + k] = bf_[t * 4 + k];
    }
    stage_mixed(part1, 384, 8, b * 32, part1, 384, 8, 128 + b * 32, n0, t, AL);
    __syncthreads();

    int j = t & 31, nb = t >> 5;
    float acc[4][16];
    #pragma unroll
    for (int u = 0; u < 4; u++)
        #pragma unroll
        for (int g = 0; g < 8; g++) {
            acc[u][g * 2]     = BL[g * 64 + j];
            acc[u][g * 2 + 1] = BL[g * 64 + 32 + j];
        }
    #pragma unroll 2
    for (int f = 0; f < 32; f++) {
        float wls[8], wrs[8];
        #pragma unroll
        for (int g = 0; g < 8; g++) {
            uint32_t wv = WL[g * 1024 + f * 32 + j];
            wls[g] = __uint_as_float(wv << 16);
            wrs[g] = __uint_as_float(wv & 0xFFFF0000u);
        }
        #pragma unroll
        for (int u = 0; u < 4; u++) {
            int node = nb + u * 8;
            float ax = AL[node][f], ah = AL[node][32 + f];
            #pragma unroll
            for (int g = 0; g < 8; g++) {
                float src = (g & 1) ? ah : ax;
                acc[u][g * 2]     += src * wls[g];
                acc[u][g * 2 + 1] += src * wrs[g];
            }
        }
    }
    #pragma unroll
    for (int u = 0; u < 4; u++) {
        int node = nb + u * 8;
        float fx = acc[u][0]  * sig_acc(acc[u][1]);
        float fh = acc[u][2]  * sig_acc(acc[u][3]);
        float ix = acc[u][4]  * sig_acc(acc[u][5]);
        float ih = acc[u][6]  * sig_acc(acc[u][7]);
        float cx = acc[u][8]  * sig_acc(acc[u][9]);
        float ch = acc[u][10] * sig_acc(acc[u][11]);
        float ox = acc[u][12] * sig_acc(acc[u][13]);
        float oh = acc[u][14] * sig_acc(acc[u][15]);
        float fg = sig_acc(fx + fh), ig = sig_acc(ix + ih), og = sig_acc(ox + oh);
        size_t gidx = ((size_t)(b * NN + n0 + node)) * FF + j;
        float cvv = cf[gidx];
        float cn = fg * cvv + ig * tanhf(cx + ch);
        float h1 = og * tanhf(cn);
        cnew[gidx] = cn;
        H1[j][node] = f2bf(h1);
    }
    __syncthreads();
    {
        int fr = t >> 3, ch = t & 7;
        union { uint2 u; uint16_t e[4]; } v;
        #pragma unroll
        for (int k = 0; k < 4; k++) v.e[k] = H1[fr][ch * 4 + k];
        *(uint2*)(P2 + ((size_t)(b * 32 + fr)) * NN + n0 + ch * 4) = v.u;
    }
}

// ---------- fuse2: 6-gate GLU + memory-state; h_new, m_new (fp32) ----------
__global__ __launch_bounds__(256) void fuse2_k(
    const float* __restrict__ part2, const float* __restrict__ part1,
    const float* __restrict__ Wf, const float* __restrict__ bf_,
    const float* __restrict__ mf,
    float* __restrict__ hnew, float* __restrict__ mnew)
{
    __shared__ uint32_t WL[6144];
    __shared__ float BL[384];
    __shared__ float AL[32][65];

    int t = threadIdx.x;
    int bid = blockIdx.x;
    int b = bid >> 7, n0 = (bid & 127) * 32;

    for (int i = t; i < 6144; i += 256) {
        int g = i >> 10, rem = i & 1023, f = rem >> 5, j = rem & 31;
        int gg = 8 + g;
        uint32_t lo = f2bf(Wf[gg * 2048 + f * 64 + j]);
        uint32_t hi = f2bf(Wf[gg * 2048 + f * 64 + 32 + j]);
        WL[i] = lo | (hi << 16);
    }
    if (t < 96) {
        #pragma unroll
        for (int k = 0; k < 4; k++) BL[t * 4 + k] = bf_[512 + t * 4 + k];
    }
    // ah1 from part2 (cw=128, ns=16); am from part1 (cw=384, ns=8, cols 256..)
    stage_mixed(part2, 128, 16, b * 32, part1, 384, 8, 256 + b * 32, n0, t, AL);
    __syncthreads();

    int j = t & 31, nb = t >> 5;
    float acc[4][12];
    #pragma unroll
    for (int u = 0; u < 4; u++)
        #pragma unroll
        for (int g = 0; g < 6; g++) {
            acc[u][g * 2]     = BL[g * 64 + j];
            acc[u][g * 2 + 1] = BL[g * 64 + 32 + j];
        }
    #pragma unroll 2
    for (int f = 0; f < 32; f++) {
        float wls[6], wrs[6];
        #pragma unroll
        for (int g = 0; g < 6; g++) {
            uint32_t wv = WL[g * 1024 + f * 32 + j];
            wls[g] = __uint_as_float(wv << 16);
            wrs[g] = __uint_as_float(wv & 0xFFFF0000u);
        }
        #pragma unroll
        for (int u = 0; u < 4; u++) {
            int node = nb + u * 8;
            float ah1 = AL[node][f], am = AL[node][32 + f];
            #pragma unroll
            for (int g = 0; g < 6; g++) {
                float src = (g & 1) ? am : ah1;
                acc[u][g * 2]     += src * wls[g];
                acc[u][g * 2 + 1] += src * wrs[g];
            }
        }
    }
    #pragma unroll
    for (int u = 0; u < 4; u++) {
        int node = nb + u * 8;
        float sa_ih = acc[u][0]  * sig_acc(acc[u][1]);
        float sa_im = acc[u][2]  * sig_acc(acc[u][3]);
        float sa_gh = acc[u][4]  * sig_acc(acc[u][5]);
        float sa_gm = acc[u][6]  * sig_acc(acc[u][7]);
        float sa_oh = acc[u][8]  * sig_acc(acc[u][9]);
        float sa_om = acc[u][10] * sig_acc(acc[u][11]);
        float i2 = sig_acc(sa_ih + sa_im);
        float g2 = sig_acc(sa_gh + sa_gm);
        float o2 = sig_acc(sa_oh + sa_om);
        size_t gidx = ((size_t)(b * NN + n0 + node)) * FF + j;
        float mvv = mf[gidx];
        float mn = i2 * mvv + (1.0f - i2) * g2;
        float hn = mn * o2;
        mnew[gidx] = mn;
        hnew[gidx] = hn;
    }
}

extern "C" void kernel_launch(void* const* d_in, const int* in_sizes, int n_in,
                              void* d_out, int out_size, void* d_ws, size_t ws_size,
                              hipStream_t stream) {
    (void)in_sizes; (void)n_in; (void)out_size;
    const float* x   = (const float*)d_in[0];
    const float* h   = (const float*)d_in[1];
    const float* c   = (const float*)d_in[2];
    const float* m   = (const float*)d_in[3];
    const float* adj = (const float*)d_in[4];
    const float* W   = (const float*)d_in[5];
    const float* bb  = (const float*)d_in[6];
    float* out = (float*)d_out;

    char* ws = (char*)d_ws;
    uint16_t* adjb  = (uint16_t*)ws;                   // 32 MB bf16 adj
    uint16_t* P1    = (uint16_t*)(ws + (32u << 20));   // 3 MB  [x|h|m] packed
    uint16_t* P2    = (uint16_t*)(ws + (35u << 20));   // 1 MB  h1 packed
    float*    part1 = (float*)(ws + (36u << 20));      // 48 MB [8][4096][384]
    float*    part2 = (float*)(ws + (84u << 20));      // 32 MB [16][4096][128]
    if (ws_size < (size_t)(120u << 20)) return;

    // 5 dispatches (~10us/dispatch node overhead measured R5/R6/R9)
    prep_k<<<8960, 256, 0, stream>>>(x, h, m, adj, P1, adjb);
    gemm_k<<<dim3(64, 3, 8), 256, 0, stream>>>(adjb, P1, part1, 384, 512);
    fuse1_k<<<512, 256, 0, stream>>>(part1, W, bb, c, out + BNF, P2);
    gemm_k<<<dim3(64, 1, 16), 256, 0, stream>>>(adjb, P2, part2, 128, 256);
    fuse2_k<<<512, 256, 0, stream>>>(part2, part1, W, bb, m, out, out + 2 * BNF);
}